// Round 4
// baseline (657.889 us; speedup 1.0000x reference)
//
#include <hip/hip_runtime.h>

typedef unsigned int u32;
typedef unsigned short u16;
typedef __attribute__((ext_vector_type(8))) short short8;
typedef __attribute__((ext_vector_type(16))) float f32x16;

// Problem constants
#define NA   50000      // atoms
#define MN   12         // neighbors
#define FD   128        // atom feature len
#define KD   64         // nbr feature len
#define NMR  600000     // NA*MN edge rows
#define KIN  320        // 2F+K
#define NTT  6250       // NMR/96 atom-aligned tiles (8 atoms each)
#define NBLK 768        // persistent blocks for pass A/B (3 per CU)
#define QSTR 264        // LDS row stride (u16) for Q stage: 16B pad kills bank conflicts
#define BN_EPS 1e-5f
#define LOG2E 1.4426950408889634f
#define LN2   0.6931471805599453f

// ---- fast transcendentals: raw v_exp_f32 / v_log_f32 / v_rcp_f32 ----
#if __has_builtin(__builtin_amdgcn_exp2f)
#define EXP2F(x) __builtin_amdgcn_exp2f(x)
#else
#define EXP2F(x) exp2f(x)
#endif
#if __has_builtin(__builtin_amdgcn_logf)
#define LOG2F(x) __builtin_amdgcn_logf(x)
#else
#define LOG2F(x) log2f(x)
#endif
#if __has_builtin(__builtin_amdgcn_rcpf)
#define RCPF(x) __builtin_amdgcn_rcpf(x)
#else
#define RCPF(x) (1.f / (x))
#endif

__device__ __forceinline__ float fast_sigmoid(float x) {
    return RCPF(1.f + EXP2F(-x * LOG2E));
}
__device__ __forceinline__ float fast_softplus(float x) {
    float e = EXP2F(-fabsf(x) * LOG2E);
    return fmaxf(x, 0.f) + LN2 * LOG2F(1.f + e);
}

// ---- manual bf16 (RNE) helpers ----
__device__ __forceinline__ u32 f2bf_bits(float f) {
    u32 u = __float_as_uint(f);
    return u + 0x7fffu + ((u >> 16) & 1u);
}
__device__ __forceinline__ u32 pack2(float lo, float hi) {
    return (f2bf_bits(lo) >> 16) | (f2bf_bits(hi) & 0xffff0000u);
}
__device__ __forceinline__ float bflo(u32 u) { return __uint_as_float(u << 16); }
__device__ __forceinline__ float bfhi(u32 u) { return __uint_as_float(u & 0xffff0000u); }
__device__ __forceinline__ short8 pack8(float4 x, float4 y) {
    union { short8 s; uint4 u; } cv;
    cv.u = make_uint4(pack2(x.x, x.y), pack2(x.z, x.w),
                      pack2(y.x, y.y), pack2(y.z, y.w));
    return cv.s;
}
__device__ __forceinline__ void unp4(uint2 u, float* f) {
    f[0] = bflo(u.x); f[1] = bfhi(u.x); f[2] = bflo(u.y); f[3] = bfhi(u.y);
}

// ---------------------------------------------------------------------------
// K1 (MFMA): P12[n][0:256] = atom@W1^T, [256:512] = atom@W2^T, bf16 out.
// Bias skipped (cancels through BN1 mean). Stationary B in VGPRs, K=128
// fully unrolled, zero LDS.
// ---------------------------------------------------------------------------
__global__ __launch_bounds__(256) void k1_p12(const float* __restrict__ atom,
                                              const float* __restrict__ W,
                                              u16* __restrict__ P12) {
    const int t  = threadIdx.x;
    const int w  = t >> 6;
    const int L  = t & 63;
    const int rg = w & 1, cg = w >> 1;
    const int lr = L & 31, lk = L >> 5;
    const int yb  = blockIdx.y;
    const int kwb = yb * 128;
    const int r0  = blockIdx.x * 64 + rg * 32;

    short8 bfrag[4][8];
#pragma unroll
    for (int ct = 0; ct < 4; ct++) {
        const float* wr = &W[(size_t)(cg * 128 + ct * 32 + lr) * KIN + kwb];
#pragma unroll
        for (int s = 0; s < 8; s++) {
            float4 x = *(const float4*)&wr[s * 16 + lk * 8];
            float4 y = *(const float4*)&wr[s * 16 + lk * 8 + 4];
            bfrag[ct][s] = pack8(x, y);
        }
    }
    int row = r0 + lr; if (row > NA - 1) row = NA - 1;
    const float* ar = &atom[(size_t)row * FD];
    short8 afrag[8];
#pragma unroll
    for (int s = 0; s < 8; s++) {
        float4 x = *(const float4*)&ar[s * 16 + lk * 8];
        float4 y = *(const float4*)&ar[s * 16 + lk * 8 + 4];
        afrag[s] = pack8(x, y);
    }
    f32x16 acc[4];
#pragma unroll
    for (int ct = 0; ct < 4; ct++)
#pragma unroll
        for (int p = 0; p < 16; p++) acc[ct][p] = 0.f;
#pragma unroll
    for (int s = 0; s < 8; s++)
#pragma unroll
        for (int ct = 0; ct < 4; ct++)
            acc[ct] = __builtin_amdgcn_mfma_f32_32x32x16_bf16(
                          afrag[s], bfrag[ct][s], acc[ct], 0, 0, 0);
#pragma unroll
    for (int ct = 0; ct < 4; ct++) {
        const int c = cg * 128 + ct * 32 + lr;
#pragma unroll
        for (int p = 0; p < 16; p++) {
            int r = r0 + (p & 3) + 8 * (p >> 2) + 4 * lk;
            if (r < NA)
                P12[(size_t)r * 512 + yb * 256 + c] =
                    (u16)(f2bf_bits(acc[ct][p]) >> 16);
        }
    }
}

// ---------------------------------------------------------------------------
// Shared main-loop macro body for pass A/B: per 96-row tile (8 atoms),
// compute Q = nbr@W3^T via MFMA (wave w -> cols w*64..w*64+63, all 3
// row-groups sequentially to keep VGPR low), stage bf16 into LDS Q[96][QSTR].
// ---------------------------------------------------------------------------
#define PASS_PROLOG                                                            \
    const int t  = threadIdx.x;                                                \
    const int w  = t >> 6;                                                     \
    const int L  = t & 63;                                                     \
    const int lr = L & 31, lk = L >> 5;                                        \
    short8 bfrag[2][4];                                                        \
    _Pragma("unroll")                                                          \
    for (int ct = 0; ct < 2; ct++) {                                           \
        const float* wr = &W[(size_t)(w * 64 + ct * 32 + lr) * KIN + 256];     \
        _Pragma("unroll")                                                      \
        for (int s = 0; s < 4; s++) {                                          \
            float4 x = *(const float4*)&wr[s * 16 + lk * 8];                   \
            float4 y = *(const float4*)&wr[s * 16 + lk * 8 + 4];               \
            bfrag[ct][s] = pack8(x, y);                                        \
        }                                                                      \
    }                                                                          \
    const int ea  = t >> 5;          /* epilogue atom slot 0..7 */             \
    const int ec4 = (t & 31) * 4;    /* epilogue col group (filter) */

#define TILE_COMPUTE_STAGE(g0)                                                 \
    _Pragma("unroll")                                                          \
    for (int rg = 0; rg < 3; rg++) {                                           \
        const float* ar = &nbr[(size_t)((g0) + rg * 32 + lr) * KD];            \
        short8 af[4];                                                          \
        _Pragma("unroll")                                                      \
        for (int s = 0; s < 4; s++) {                                          \
            float4 x = *(const float4*)&ar[s * 16 + lk * 8];                   \
            float4 y = *(const float4*)&ar[s * 16 + lk * 8 + 4];               \
            af[s] = pack8(x, y);                                               \
        }                                                                      \
        f32x16 acc[2];                                                         \
        _Pragma("unroll")                                                      \
        for (int ct = 0; ct < 2; ct++)                                         \
            _Pragma("unroll")                                                  \
            for (int p = 0; p < 16; p++) acc[ct][p] = 0.f;                     \
        _Pragma("unroll")                                                      \
        for (int s = 0; s < 4; s++)                                            \
            _Pragma("unroll")                                                  \
            for (int ct = 0; ct < 2; ct++)                                     \
                acc[ct] = __builtin_amdgcn_mfma_f32_32x32x16_bf16(             \
                              af[s], bfrag[ct][s], acc[ct], 0, 0, 0);          \
        _Pragma("unroll")                                                      \
        for (int ct = 0; ct < 2; ct++) {                                       \
            const int col = w * 64 + ct * 32 + lr;                             \
            _Pragma("unroll")                                                  \
            for (int p = 0; p < 16; p++) {                                     \
                int r = rg * 32 + (p & 3) + 8 * (p >> 2) + 4 * lk;             \
                Q[r * QSTR + col] = (u16)(f2bf_bits(acc[ct][p]) >> 16);        \
            }                                                                  \
        }                                                                      \
    }

// ---------------------------------------------------------------------------
// Pass A (k2s): BN1 column sum/sumsq of gated = P1 + mk*(P2 + Q).
// No global store of gated — recompute in pass B.
// ---------------------------------------------------------------------------
__global__ __launch_bounds__(256, 3) void k2s(const float* __restrict__ nbr,
                                              const int* __restrict__ nidx,
                                              const float* __restrict__ W,
                                              const u16* __restrict__ P12,
                                              float* __restrict__ partial1) {
    __shared__ u16 Q[96 * QSTR];
    PASS_PROLOG
    float ssum[8], ssq[8];
#pragma unroll
    for (int j = 0; j < 8; j++) { ssum[j] = 0.f; ssq[j] = 0.f; }

    for (int tile = blockIdx.x; tile < NTT; tile += NBLK) {
        const int g0 = tile * 96;
        TILE_COMPUTE_STAGE(g0)
        __syncthreads();
        // epilogue: thread = (atom ea, 4 filter cols ec4 / 4 core cols 128+ec4)
        const int n = tile * 8 + ea;
        const u16* p1 = &P12[(size_t)n * 512];
        float f1[4], c1[4];
        unp4(*(const uint2*)&p1[ec4], f1);
        unp4(*(const uint2*)&p1[128 + ec4], c1);
        const int gb = n * MN;
#pragma unroll
        for (int m = 0; m < MN; m++) {
            const int iv = nidx[gb + m];
            const float mk = (iv != 0) ? 1.f : 0.f;
            const u16* p2 = &P12[(size_t)iv * 512 + 256];
            float pf[4], pc[4], qf[4], qc[4];
            unp4(*(const uint2*)&p2[ec4], pf);
            unp4(*(const uint2*)&p2[128 + ec4], pc);
            unp4(*(const uint2*)&Q[(ea * MN + m) * QSTR + ec4], qf);
            unp4(*(const uint2*)&Q[(ea * MN + m) * QSTR + 128 + ec4], qc);
#pragma unroll
            for (int j = 0; j < 4; j++) {
                float vf = f1[j] + mk * (pf[j] + qf[j]);
                float vc = c1[j] + mk * (pc[j] + qc[j]);
                ssum[j]     += vf; ssq[j]     += vf * vf;
                ssum[4 + j] += vc; ssq[4 + j] += vc * vc;
            }
        }
        __syncthreads();   // protect LDS before next tile's staging
    }
    // block reduction over the 8 atom-groups -> partial1[block][512]
    float* red = (float*)Q;   // 8*256 floats = 8 KB
#pragma unroll
    for (int j = 0; j < 4; j++) {
        red[ea * 256 + ec4 + j]       = ssum[j];
        red[ea * 256 + 128 + ec4 + j] = ssum[4 + j];
    }
    __syncthreads();
    {
        float s = 0.f;
#pragma unroll
        for (int a = 0; a < 8; a++) s += red[a * 256 + t];
        partial1[(size_t)blockIdx.x * 512 + t] = s;
    }
    __syncthreads();
#pragma unroll
    for (int j = 0; j < 4; j++) {
        red[ea * 256 + ec4 + j]       = ssq[j];
        red[ea * 256 + 128 + ec4 + j] = ssq[4 + j];
    }
    __syncthreads();
    {
        float s = 0.f;
#pragma unroll
        for (int a = 0; a < 8; a++) s += red[a * 256 + t];
        partial1[(size_t)blockIdx.x * 512 + 256 + t] = s;
    }
}

// ---------------------------------------------------------------------------
// K2b: finalize BN1 -> bn1[c]=scale, bn1[256+c]=shift
// ---------------------------------------------------------------------------
__global__ __launch_bounds__(64) void k2b_bn1(const float* __restrict__ partial1,
                                              const float* __restrict__ gamma1,
                                              const float* __restrict__ beta1,
                                              float* __restrict__ bn1) {
    const int c = blockIdx.x;
    const int t = threadIdx.x;
    double s = 0.0, q = 0.0;
    for (int b = t; b < NBLK; b += 64) {
        s += (double)partial1[(size_t)b * 512 + c];
        q += (double)partial1[(size_t)b * 512 + 256 + c];
    }
#pragma unroll
    for (int off = 32; off > 0; off >>= 1) {
        s += __shfl_down(s, off);
        q += __shfl_down(q, off);
    }
    if (t == 0) {
        double mean = s / (double)NMR;
        double var  = q / (double)NMR - mean * mean;
        float scale = gamma1[c] * rsqrtf((float)var + BN_EPS);
        bn1[c]       = scale;
        bn1[256 + c] = fmaf(-(float)mean, scale, beta1[c]);
    }
}

// ---------------------------------------------------------------------------
// Pass B (k3r): recompute Q, gated = P1 + mk*(P2+Q); BN1 + sigmoid*softplus*
// mask; sum over the 12 in-tile rows per atom -> nsum; BN2 partials.
// ---------------------------------------------------------------------------
__global__ __launch_bounds__(256, 3) void k3r(const float* __restrict__ nbr,
                                              const int* __restrict__ nidx,
                                              const float* __restrict__ W,
                                              const u16* __restrict__ P12,
                                              const float* __restrict__ bn1,
                                              float* __restrict__ nsum,
                                              float* __restrict__ partial2) {
    __shared__ u16 Q[96 * QSTR];
    PASS_PROLOG
    float scf[4], shf[4], scc[4], shc[4];
#pragma unroll
    for (int j = 0; j < 4; j++) {
        scf[j] = bn1[ec4 + j];       shf[j] = bn1[256 + ec4 + j];
        scc[j] = bn1[128 + ec4 + j]; shc[j] = bn1[384 + ec4 + j];
    }
    float bsum[4] = {0.f, 0.f, 0.f, 0.f};
    float bsq[4]  = {0.f, 0.f, 0.f, 0.f};

    for (int tile = blockIdx.x; tile < NTT; tile += NBLK) {
        const int g0 = tile * 96;
        TILE_COMPUTE_STAGE(g0)
        __syncthreads();
        const int n = tile * 8 + ea;
        const u16* p1 = &P12[(size_t)n * 512];
        float f1[4], c1[4];
        unp4(*(const uint2*)&p1[ec4], f1);
        unp4(*(const uint2*)&p1[128 + ec4], c1);
        const int gb = n * MN;
        float acc4[4] = {0.f, 0.f, 0.f, 0.f};
#pragma unroll
        for (int m = 0; m < MN; m++) {
            const int iv = nidx[gb + m];
            const float mk = (iv != 0) ? 1.f : 0.f;
            const u16* p2 = &P12[(size_t)iv * 512 + 256];
            float pf[4], pc[4], qf[4], qc[4];
            unp4(*(const uint2*)&p2[ec4], pf);
            unp4(*(const uint2*)&p2[128 + ec4], pc);
            unp4(*(const uint2*)&Q[(ea * MN + m) * QSTR + ec4], qf);
            unp4(*(const uint2*)&Q[(ea * MN + m) * QSTR + 128 + ec4], qc);
#pragma unroll
            for (int j = 0; j < 4; j++) {
                float gf = f1[j] + mk * (pf[j] + qf[j]);
                float gc = c1[j] + mk * (pc[j] + qc[j]);
                float xf = fmaf(gf, scf[j], shf[j]);
                float xc = fmaf(gc, scc[j], shc[j]);
                acc4[j] += fast_sigmoid(xf) * fast_softplus(xc) * mk;
            }
        }
        *(float4*)&nsum[(size_t)n * 128 + ec4] =
            make_float4(acc4[0], acc4[1], acc4[2], acc4[3]);
#pragma unroll
        for (int j = 0; j < 4; j++) {
            bsum[j] += acc4[j];
            bsq[j]  += acc4[j] * acc4[j];
        }
        __syncthreads();
    }
    // block reduction (8 atom-groups) -> partial2[block][256]
    float* red = (float*)Q;   // 8*128 floats
#pragma unroll
    for (int j = 0; j < 4; j++) red[ea * 128 + ec4 + j] = bsum[j];
    __syncthreads();
    if (t < 128) {
        float s = 0.f;
#pragma unroll
        for (int a = 0; a < 8; a++) s += red[a * 128 + t];
        partial2[(size_t)blockIdx.x * 256 + t] = s;
    }
    __syncthreads();
#pragma unroll
    for (int j = 0; j < 4; j++) red[ea * 128 + ec4 + j] = bsq[j];
    __syncthreads();
    if (t < 128) {
        float s = 0.f;
#pragma unroll
        for (int a = 0; a < 8; a++) s += red[a * 128 + t];
        partial2[(size_t)blockIdx.x * 256 + 128 + t] = s;
    }
}

// ---------------------------------------------------------------------------
// K3b: finalize BN2 -> bn2[c]=scale, bn2[128+c]=shift
// ---------------------------------------------------------------------------
__global__ __launch_bounds__(64) void k3b_bn2(const float* __restrict__ partial2,
                                              const float* __restrict__ gamma2,
                                              const float* __restrict__ beta2,
                                              float* __restrict__ bn2) {
    const int c = blockIdx.x;
    const int t = threadIdx.x;
    double s = 0.0, q = 0.0;
    for (int b = t; b < NBLK; b += 64) {
        s += (double)partial2[(size_t)b * 256 + c];
        q += (double)partial2[(size_t)b * 256 + 128 + c];
    }
#pragma unroll
    for (int off = 32; off > 0; off >>= 1) {
        s += __shfl_down(s, off);
        q += __shfl_down(q, off);
    }
    if (t == 0) {
        double mean = s / (double)NA;
        double var  = q / (double)NA - mean * mean;
        float scale = gamma2[c] * rsqrtf((float)var + BN_EPS);
        bn2[c]       = scale;
        bn2[128 + c] = fmaf(-(float)mean, scale, beta2[c]);
    }
}

// ---------------------------------------------------------------------------
// K4: out = softplus(atom_in + nbr_sumed*scale2 + shift2)
// ---------------------------------------------------------------------------
__global__ __launch_bounds__(256) void k4_out(const float* __restrict__ atom,
                                              const float* __restrict__ nsum,
                                              const float* __restrict__ bn2,
                                              float* __restrict__ out) {
    const int i  = blockIdx.x * 256 + threadIdx.x;   // float4 index, 1.6M exact
    const int c0 = (i & 31) * 4;
    float4 a = ((const float4*)atom)[i];
    float4 s = ((const float4*)nsum)[i];
    float4 r;
    r.x = fast_softplus(a.x + fmaf(s.x, bn2[c0 + 0], bn2[128 + c0 + 0]));
    r.y = fast_softplus(a.y + fmaf(s.y, bn2[c0 + 1], bn2[128 + c0 + 1]));
    r.z = fast_softplus(a.z + fmaf(s.z, bn2[c0 + 2], bn2[128 + c0 + 2]));
    r.w = fast_softplus(a.w + fmaf(s.w, bn2[c0 + 3], bn2[128 + c0 + 3]));
    ((float4*)out)[i] = r;
}

// ---------------------------------------------------------------------------
extern "C" void kernel_launch(void* const* d_in, const int* in_sizes, int n_in,
                              void* d_out, int out_size, void* d_ws, size_t ws_size,
                              hipStream_t stream) {
    const float* atom   = (const float*)d_in[0];
    const float* nbr    = (const float*)d_in[1];
    const int*   nidx   = (const int*)d_in[2];
    const float* W      = (const float*)d_in[3];
    // d_in[4] = b : unused — cancels exactly through BN1 mean subtraction
    const float* gamma1 = (const float*)d_in[5];
    const float* beta1  = (const float*)d_in[6];
    const float* gamma2 = (const float*)d_in[7];
    const float* beta2  = (const float*)d_in[8];
    float* out = (float*)d_out;

    // ws layout: P12 bf16 (51.2MB) | nsum f32 (25.6MB) | partials | bn — ~78MB
    u16* P12 = (u16*)d_ws;
    float* nsum     = (float*)(P12 + (size_t)NA * 512);
    float* partial1 = nsum + (size_t)NA * 128;
    float* partial2 = partial1 + (size_t)NBLK * 512;
    float* bn1      = partial2 + (size_t)NBLK * 256;
    float* bn2      = bn1 + 512;

    k1_p12 <<<dim3(782, 2), 256, 0, stream>>>(atom, W, P12);
    k2s    <<<NBLK,         256, 0, stream>>>(nbr, nidx, W, P12, partial1);
    k2b_bn1<<<256,           64, 0, stream>>>(partial1, gamma1, beta1, bn1);
    k3r    <<<NBLK,         256, 0, stream>>>(nbr, nidx, W, P12, bn1, nsum, partial2);
    k3b_bn2<<<128,           64, 0, stream>>>(partial2, gamma2, beta2, bn2);
    k4_out <<<6250,         256, 0, stream>>>(atom, nsum, bn2, out);
}

// Round 5
// 567.440 us; speedup vs baseline: 1.1594x; 1.1594x over previous
//
#include <hip/hip_runtime.h>

typedef unsigned int u32;
typedef unsigned short u16;
typedef __attribute__((ext_vector_type(8))) short short8;
typedef __attribute__((ext_vector_type(16))) float f32x16;

// Problem constants
#define NA   50000      // atoms
#define MN   12         // neighbors
#define FD   128        // atom feature len
#define KD   64         // nbr feature len
#define NMR  600000     // NA*MN edge rows
#define KIN  320        // 2F+K
#define NT2  9375       // NMR/64 edge tiles
#define NBLK2 512       // persistent blocks for pass A/B (2 per CU)
#define NBLK3 256       // k3s stat blocks
#define BN_EPS 1e-5f
#define LOG2E 1.4426950408889634f
#define LN2   0.6931471805599453f

// ---- fast transcendentals ----
#if __has_builtin(__builtin_amdgcn_exp2f)
#define EXP2F(x) __builtin_amdgcn_exp2f(x)
#else
#define EXP2F(x) exp2f(x)
#endif
#if __has_builtin(__builtin_amdgcn_logf)
#define LOG2F(x) __builtin_amdgcn_logf(x)
#else
#define LOG2F(x) log2f(x)
#endif
#if __has_builtin(__builtin_amdgcn_rcpf)
#define RCPF(x) __builtin_amdgcn_rcpf(x)
#else
#define RCPF(x) (1.f / (x))
#endif

__device__ __forceinline__ float fast_sigmoid(float x) {
    return RCPF(1.f + EXP2F(-x * LOG2E));
}
__device__ __forceinline__ float fast_softplus(float x) {
    float e = EXP2F(-fabsf(x) * LOG2E);
    return fmaxf(x, 0.f) + LN2 * LOG2F(1.f + e);
}

// ---- manual bf16 (RNE) helpers ----
__device__ __forceinline__ u32 f2bf_bits(float f) {
    u32 u = __float_as_uint(f);
    return u + 0x7fffu + ((u >> 16) & 1u);
}
__device__ __forceinline__ u32 pack2(float lo, float hi) {
    return (f2bf_bits(lo) >> 16) | (f2bf_bits(hi) & 0xffff0000u);
}
__device__ __forceinline__ float bflo(u32 u) { return __uint_as_float(u << 16); }
__device__ __forceinline__ float bfhi(u32 u) { return __uint_as_float(u & 0xffff0000u); }
__device__ __forceinline__ short8 pack8(float4 x, float4 y) {
    union { short8 s; uint4 u; } cv;
    cv.u = make_uint4(pack2(x.x, x.y), pack2(x.z, x.w),
                      pack2(y.x, y.y), pack2(y.z, y.w));
    return cv.s;
}

// ---------------------------------------------------------------------------
// K1 (MFMA): P12[n][0:256] = atom@W1^T, [256:512] = atom@W2^T, bf16 out.
// Bias skipped (cancels through BN1 mean). Sequential ct-tiles keep peak
// VGPR ~100 (no spill). One block does both yb halves (atom read once).
// ---------------------------------------------------------------------------
__global__ __launch_bounds__(256) void k1_p12(const float* __restrict__ atom,
                                              const float* __restrict__ W,
                                              u16* __restrict__ P12) {
    const int t  = threadIdx.x;
    const int w  = t >> 6;
    const int L  = t & 63;
    const int rg = w & 1, cg = w >> 1;
    const int lr = L & 31, lk = L >> 5;
    const int r0 = blockIdx.x * 64 + rg * 32;

    int row = r0 + lr; if (row > NA - 1) row = NA - 1;
    const float* ar = &atom[(size_t)row * FD];
    short8 afrag[8];
#pragma unroll
    for (int s = 0; s < 8; s++) {
        float4 x = *(const float4*)&ar[s * 16 + lk * 8];
        float4 y = *(const float4*)&ar[s * 16 + lk * 8 + 4];
        afrag[s] = pack8(x, y);
    }
#pragma unroll
    for (int yb = 0; yb < 2; yb++) {
        const int kwb = yb * 128;
#pragma unroll
        for (int ct = 0; ct < 4; ct++) {
            const float* wr = &W[(size_t)(cg * 128 + ct * 32 + lr) * KIN + kwb];
            short8 bf[8];
#pragma unroll
            for (int s = 0; s < 8; s++) {
                float4 x = *(const float4*)&wr[s * 16 + lk * 8];
                float4 y = *(const float4*)&wr[s * 16 + lk * 8 + 4];
                bf[s] = pack8(x, y);
            }
            f32x16 acc;
#pragma unroll
            for (int p = 0; p < 16; p++) acc[p] = 0.f;
#pragma unroll
            for (int s = 0; s < 8; s++)
                acc = __builtin_amdgcn_mfma_f32_32x32x16_bf16(
                          afrag[s], bf[s], acc, 0, 0, 0);
            const int c = cg * 128 + ct * 32 + lr;
#pragma unroll
            for (int p = 0; p < 16; p++) {
                int r = r0 + (p & 3) + 8 * (p >> 2) + 4 * lk;
                if (r < NA)
                    P12[(size_t)r * 512 + yb * 256 + c] =
                        (u16)(f2bf_bits(acc[p]) >> 16);
            }
        }
    }
}

// ---------------------------------------------------------------------------
// Pass A (k2s): Q = nbr@W3^T (MFMA, stationary B in VGPRs), C staged through
// LDS; epilogue gathers P1/P2, forms gated in registers, accumulates BN1
// column sum/sumsq. NO global store of gated (recomputed in pass B).
// Proven R3 skeleton: wave w -> rows 32*(w&1), cols 128*(w>>1), VGPR ~124.
// ---------------------------------------------------------------------------
__global__ __launch_bounds__(256, 2) void k2s(const float* __restrict__ nbr,
                                              const int* __restrict__ nidx,
                                              const float* __restrict__ W,
                                              const u16* __restrict__ P12,
                                              float* __restrict__ partial1) {
    __shared__ float C_lds[64 * 256];     // 64 KB
    const int t  = threadIdx.x;
    const int w  = t >> 6;
    const int L  = t & 63;
    const int rg = w & 1;
    const int cg = w >> 1;
    const int lr = L & 31;
    const int lk = L >> 5;

    short8 bfrag[4][4];
#pragma unroll
    for (int ct = 0; ct < 4; ct++) {
        const float* wr = &W[(size_t)(cg * 128 + ct * 32 + lr) * KIN + 256];
#pragma unroll
        for (int s = 0; s < 4; s++) {
            float4 x = *(const float4*)&wr[s * 16 + lk * 8];
            float4 y = *(const float4*)&wr[s * 16 + lk * 8 + 4];
            bfrag[ct][s] = pack8(x, y);
        }
    }

    const int c0 = (t & 63) * 4;
    float ssum[4] = {0.f, 0.f, 0.f, 0.f};
    float ssq[4]  = {0.f, 0.f, 0.f, 0.f};

    int tile = blockIdx.x;
    float4 a0[4], a1[4];
    {
        const float* ar = &nbr[(size_t)(tile * 64 + rg * 32 + lr) * KD];
#pragma unroll
        for (int s = 0; s < 4; s++) {
            a0[s] = *(const float4*)&ar[s * 16 + lk * 8];
            a1[s] = *(const float4*)&ar[s * 16 + lk * 8 + 4];
        }
    }

    for (; tile < NT2; tile += NBLK2) {
        short8 af[4];
#pragma unroll
        for (int s = 0; s < 4; s++) af[s] = pack8(a0[s], a1[s]);

        const int next = tile + NBLK2;
        if (next < NT2) {
            const float* ar = &nbr[(size_t)(next * 64 + rg * 32 + lr) * KD];
#pragma unroll
            for (int s = 0; s < 4; s++) {
                a0[s] = *(const float4*)&ar[s * 16 + lk * 8];
                a1[s] = *(const float4*)&ar[s * 16 + lk * 8 + 4];
            }
        }

        f32x16 acc[4];
#pragma unroll
        for (int ct = 0; ct < 4; ct++)
#pragma unroll
            for (int p = 0; p < 16; p++) acc[ct][p] = 0.f;
#pragma unroll
        for (int s = 0; s < 4; s++)
#pragma unroll
            for (int ct = 0; ct < 4; ct++)
                acc[ct] = __builtin_amdgcn_mfma_f32_32x32x16_bf16(
                              af[s], bfrag[ct][s], acc[ct], 0, 0, 0);

        __syncthreads();   // previous tile's epilogue reads complete
#pragma unroll
        for (int ct = 0; ct < 4; ct++) {
            const int col = cg * 128 + ct * 32 + lr;
#pragma unroll
            for (int p = 0; p < 16; p++) {
                int r = rg * 32 + (p & 3) + 8 * (p >> 2) + 4 * lk;
                C_lds[r * 256 + col] = acc[ct][p];
            }
        }
        __syncthreads();

        // epilogue: wave w -> rows w, w+4, ..., w+60; stats only (no store)
#pragma unroll 8
        for (int rr = 0; rr < 16; rr++) {
            const int lrow = rr * 4 + w;
            const int g    = tile * 64 + lrow;
            const u32 n    = (u32)g / 12u;
            const int iv   = nidx[g];
            const float mk = (iv != 0) ? 1.f : 0.f;
            float4 q = *(const float4*)&C_lds[lrow * 256 + c0];
            uint2 u1 = *(const uint2*)&P12[(size_t)n * 512 + c0];
            uint2 u2 = *(const uint2*)&P12[(size_t)iv * 512 + 256 + c0];
            float v0 = bflo(u1.x) + mk * (bflo(u2.x) + q.x);
            float v1 = bfhi(u1.x) + mk * (bfhi(u2.x) + q.y);
            float v2 = bflo(u1.y) + mk * (bflo(u2.y) + q.z);
            float v3 = bfhi(u1.y) + mk * (bfhi(u2.y) + q.w);
            ssum[0] += v0; ssq[0] += v0 * v0;
            ssum[1] += v1; ssq[1] += v1 * v1;
            ssum[2] += v2; ssq[2] += v2 * v2;
            ssum[3] += v3; ssq[3] += v3 * v3;
        }
    }

    // block-level column reduction -> partial1[block][512]
    __syncthreads();
#pragma unroll
    for (int qq = 0; qq < 4; qq++) C_lds[w * 256 + c0 + qq] = ssum[qq];
    __syncthreads();
    {
        float s = C_lds[t] + C_lds[256 + t] + C_lds[512 + t] + C_lds[768 + t];
        partial1[(size_t)blockIdx.x * 512 + t] = s;
    }
    __syncthreads();
#pragma unroll
    for (int qq = 0; qq < 4; qq++) C_lds[w * 256 + c0 + qq] = ssq[qq];
    __syncthreads();
    {
        float s = C_lds[t] + C_lds[256 + t] + C_lds[512 + t] + C_lds[768 + t];
        partial1[(size_t)blockIdx.x * 512 + 256 + t] = s;
    }
}

// ---------------------------------------------------------------------------
// K2b: finalize BN1 -> bn1[c]=scale, bn1[256+c]=shift
// ---------------------------------------------------------------------------
__global__ __launch_bounds__(64) void k2b_bn1(const float* __restrict__ partial1,
                                              const float* __restrict__ gamma1,
                                              const float* __restrict__ beta1,
                                              float* __restrict__ bn1) {
    const int c = blockIdx.x;
    const int t = threadIdx.x;
    double s = 0.0, q = 0.0;
    for (int b = t; b < NBLK2; b += 64) {
        s += (double)partial1[(size_t)b * 512 + c];
        q += (double)partial1[(size_t)b * 512 + 256 + c];
    }
#pragma unroll
    for (int off = 32; off > 0; off >>= 1) {
        s += __shfl_down(s, off);
        q += __shfl_down(q, off);
    }
    if (t == 0) {
        double mean = s / (double)NMR;
        double var  = q / (double)NMR - mean * mean;
        float scale = gamma1[c] * rsqrtf((float)var + BN_EPS);
        bn1[c]       = scale;
        bn1[256 + c] = fmaf(-(float)mean, scale, beta1[c]);
    }
}

// ---------------------------------------------------------------------------
// Pass B (k3r): recompute Q (bit-identical MFMA chain), epilogue applies
// BN1 + sigmoid*softplus*mask writing act back into C_lds filter half, then
// per-atom row sums (<=6 atoms/tile) atomicAdd into nsum.
// ---------------------------------------------------------------------------
__global__ __launch_bounds__(256, 2) void k3r(const float* __restrict__ nbr,
                                              const int* __restrict__ nidx,
                                              const float* __restrict__ W,
                                              const u16* __restrict__ P12,
                                              const float* __restrict__ bn1,
                                              float* __restrict__ nsum) {
    __shared__ float C_lds[64 * 256];     // 64 KB
    const int t  = threadIdx.x;
    const int w  = t >> 6;
    const int L  = t & 63;
    const int rg = w & 1;
    const int cg = w >> 1;
    const int lr = L & 31;
    const int lk = L >> 5;

    short8 bfrag[4][4];
#pragma unroll
    for (int ct = 0; ct < 4; ct++) {
        const float* wr = &W[(size_t)(cg * 128 + ct * 32 + lr) * KIN + 256];
#pragma unroll
        for (int s = 0; s < 4; s++) {
            float4 x = *(const float4*)&wr[s * 16 + lk * 8];
            float4 y = *(const float4*)&wr[s * 16 + lk * 8 + 4];
            bfrag[ct][s] = pack8(x, y);
        }
    }

    // E1 mapping: cf = 4 filter cols, rs = row slot (8 rows, stride 8)
    const int cf = (t & 31) * 4;
    const int rs = t >> 5;
    float scf[4], shf[4], scc[4], shc[4];
#pragma unroll
    for (int j = 0; j < 4; j++) {
        scf[j] = bn1[cf + j];       shf[j] = bn1[256 + cf + j];
        scc[j] = bn1[128 + cf + j]; shc[j] = bn1[384 + cf + j];
    }
    // E2 mapping
    const int c128 = t & 127;
    const int hh   = t >> 7;

    int tile = blockIdx.x;
    float4 a0[4], a1[4];
    {
        const float* ar = &nbr[(size_t)(tile * 64 + rg * 32 + lr) * KD];
#pragma unroll
        for (int s = 0; s < 4; s++) {
            a0[s] = *(const float4*)&ar[s * 16 + lk * 8];
            a1[s] = *(const float4*)&ar[s * 16 + lk * 8 + 4];
        }
    }

    for (; tile < NT2; tile += NBLK2) {
        short8 af[4];
#pragma unroll
        for (int s = 0; s < 4; s++) af[s] = pack8(a0[s], a1[s]);

        const int next = tile + NBLK2;
        if (next < NT2) {
            const float* ar = &nbr[(size_t)(next * 64 + rg * 32 + lr) * KD];
#pragma unroll
            for (int s = 0; s < 4; s++) {
                a0[s] = *(const float4*)&ar[s * 16 + lk * 8];
                a1[s] = *(const float4*)&ar[s * 16 + lk * 8 + 4];
            }
        }

        f32x16 acc[4];
#pragma unroll
        for (int ct = 0; ct < 4; ct++)
#pragma unroll
            for (int p = 0; p < 16; p++) acc[ct][p] = 0.f;
#pragma unroll
        for (int s = 0; s < 4; s++)
#pragma unroll
            for (int ct = 0; ct < 4; ct++)
                acc[ct] = __builtin_amdgcn_mfma_f32_32x32x16_bf16(
                              af[s], bfrag[ct][s], acc[ct], 0, 0, 0);

        __syncthreads();   // previous tile's E2 reads complete
#pragma unroll
        for (int ct = 0; ct < 4; ct++) {
            const int col = cg * 128 + ct * 32 + lr;
#pragma unroll
            for (int p = 0; p < 16; p++) {
                int r = rg * 32 + (p & 3) + 8 * (p >> 2) + 4 * lk;
                C_lds[r * 256 + col] = acc[ct][p];
            }
        }
        __syncthreads();

        const int g0 = tile * 64;
        // E1: act = sigmoid(BN(filter)) * softplus(BN(core)) * mk,
        // written back into the filter half of C_lds (owner-exclusive cells).
#pragma unroll 8
        for (int rr8 = 0; rr8 < 8; rr8++) {
            const int row = rr8 * 8 + rs;
            const int g   = g0 + row;
            const u32 n   = (u32)g / 12u;
            const int iv  = nidx[g];
            const float mk = (iv != 0) ? 1.f : 0.f;
            float4 qf = *(const float4*)&C_lds[row * 256 + cf];
            float4 qc = *(const float4*)&C_lds[row * 256 + 128 + cf];
            uint2 pf1 = *(const uint2*)&P12[(size_t)n * 512 + cf];
            uint2 pc1 = *(const uint2*)&P12[(size_t)n * 512 + 128 + cf];
            uint2 pf2 = *(const uint2*)&P12[(size_t)iv * 512 + 256 + cf];
            uint2 pc2 = *(const uint2*)&P12[(size_t)iv * 512 + 384 + cf];
            float gf[4], gc[4];
            gf[0] = bflo(pf1.x) + mk * (bflo(pf2.x) + qf.x);
            gf[1] = bfhi(pf1.x) + mk * (bfhi(pf2.x) + qf.y);
            gf[2] = bflo(pf1.y) + mk * (bflo(pf2.y) + qf.z);
            gf[3] = bfhi(pf1.y) + mk * (bfhi(pf2.y) + qf.w);
            gc[0] = bflo(pc1.x) + mk * (bflo(pc2.x) + qc.x);
            gc[1] = bfhi(pc1.x) + mk * (bfhi(pc2.x) + qc.y);
            gc[2] = bflo(pc1.y) + mk * (bflo(pc2.y) + qc.z);
            gc[3] = bfhi(pc1.y) + mk * (bfhi(pc2.y) + qc.w);
            float4 act;
            act.x = fast_sigmoid(fmaf(gf[0], scf[0], shf[0])) *
                    fast_softplus(fmaf(gc[0], scc[0], shc[0])) * mk;
            act.y = fast_sigmoid(fmaf(gf[1], scf[1], shf[1])) *
                    fast_softplus(fmaf(gc[1], scc[1], shc[1])) * mk;
            act.z = fast_sigmoid(fmaf(gf[2], scf[2], shf[2])) *
                    fast_softplus(fmaf(gc[2], scc[2], shc[2])) * mk;
            act.w = fast_sigmoid(fmaf(gf[3], scf[3], shf[3])) *
                    fast_softplus(fmaf(gc[3], scc[3], shc[3])) * mk;
            *(float4*)&C_lds[row * 256 + cf] = act;
        }
        __syncthreads();

        // E2: per-atom row sums -> atomicAdd nsum (<=6 atoms per 64-row tile)
        const int na0 = g0 / 12;
        const int off = g0 - na0 * 12;
#pragma unroll
        for (int ai = 0; ai < 3; ai++) {
            const int a   = hh + ai * 2;
            int rlo = a * 12 - off;       if (rlo < 0)  rlo = 0;
            int rhi = (a + 1) * 12 - off; if (rhi > 64) rhi = 64;
            float s = 0.f;
            for (int r = rlo; r < rhi; r++) s += C_lds[r * 256 + c128];
            if (rlo < rhi)
                atomicAdd(&nsum[(size_t)(na0 + a) * 128 + c128], s);
        }
    }
}

// ---------------------------------------------------------------------------
// K3s: BN2 stats sweep over completed nsum -> partial2[block][256]
// ---------------------------------------------------------------------------
__global__ __launch_bounds__(256) void k3s(const float* __restrict__ nsum,
                                           float* __restrict__ partial2) {
    __shared__ float red[512];
    const int t  = threadIdx.x;
    const int c  = t & 127;
    const int rs = t >> 7;
    float s = 0.f, q = 0.f;
    for (int n = blockIdx.x * 2 + rs; n < NA; n += NBLK3 * 2) {
        float v = nsum[(size_t)n * 128 + c];
        s += v; q += v * v;
    }
    red[t] = s; red[256 + t] = q;
    __syncthreads();
    if (t < 128) {
        partial2[(size_t)blockIdx.x * 256 + t]       = red[t] + red[128 + t];
        partial2[(size_t)blockIdx.x * 256 + 128 + t] = red[256 + t] + red[384 + t];
    }
}

// ---------------------------------------------------------------------------
// K3b: finalize BN2 -> bn2[c]=scale, bn2[128+c]=shift
// ---------------------------------------------------------------------------
__global__ __launch_bounds__(64) void k3b_bn2(const float* __restrict__ partial2,
                                              const float* __restrict__ gamma2,
                                              const float* __restrict__ beta2,
                                              float* __restrict__ bn2) {
    const int c = blockIdx.x;
    const int t = threadIdx.x;
    double s = 0.0, q = 0.0;
    for (int b = t; b < NBLK3; b += 64) {
        s += (double)partial2[(size_t)b * 256 + c];
        q += (double)partial2[(size_t)b * 256 + 128 + c];
    }
#pragma unroll
    for (int off = 32; off > 0; off >>= 1) {
        s += __shfl_down(s, off);
        q += __shfl_down(q, off);
    }
    if (t == 0) {
        double mean = s / (double)NA;
        double var  = q / (double)NA - mean * mean;
        float scale = gamma2[c] * rsqrtf((float)var + BN_EPS);
        bn2[c]       = scale;
        bn2[128 + c] = fmaf(-(float)mean, scale, beta2[c]);
    }
}

// ---------------------------------------------------------------------------
// K4: out = softplus(atom_in + nbr_sumed*scale2 + shift2)
// ---------------------------------------------------------------------------
__global__ __launch_bounds__(256) void k4_out(const float* __restrict__ atom,
                                              const float* __restrict__ nsum,
                                              const float* __restrict__ bn2,
                                              float* __restrict__ out) {
    const int i  = blockIdx.x * 256 + threadIdx.x;   // float4 index, 1.6M exact
    const int c0 = (i & 31) * 4;
    float4 a = ((const float4*)atom)[i];
    float4 s = ((const float4*)nsum)[i];
    float4 r;
    r.x = fast_softplus(a.x + fmaf(s.x, bn2[c0 + 0], bn2[128 + c0 + 0]));
    r.y = fast_softplus(a.y + fmaf(s.y, bn2[c0 + 1], bn2[128 + c0 + 1]));
    r.z = fast_softplus(a.z + fmaf(s.z, bn2[c0 + 2], bn2[128 + c0 + 2]));
    r.w = fast_softplus(a.w + fmaf(s.w, bn2[c0 + 3], bn2[128 + c0 + 3]));
    ((float4*)out)[i] = r;
}

// ---------------------------------------------------------------------------
extern "C" void kernel_launch(void* const* d_in, const int* in_sizes, int n_in,
                              void* d_out, int out_size, void* d_ws, size_t ws_size,
                              hipStream_t stream) {
    const float* atom   = (const float*)d_in[0];
    const float* nbr    = (const float*)d_in[1];
    const int*   nidx   = (const int*)d_in[2];
    const float* W      = (const float*)d_in[3];
    // d_in[4] = b : unused — cancels exactly through BN1 mean subtraction
    const float* gamma1 = (const float*)d_in[5];
    const float* beta1  = (const float*)d_in[6];
    const float* gamma2 = (const float*)d_in[7];
    const float* beta2  = (const float*)d_in[8];
    float* out = (float*)d_out;

    // ws layout: P12 bf16 (51.2MB) | nsum f32 (25.6MB) | partials | bn
    u16* P12 = (u16*)d_ws;
    float* nsum     = (float*)(P12 + (size_t)NA * 512);
    float* partial1 = nsum + (size_t)NA * 128;
    float* partial2 = partial1 + (size_t)NBLK2 * 512;
    float* bn1      = partial2 + (size_t)NBLK3 * 256;
    float* bn2      = bn1 + 512;

    hipMemsetAsync(nsum, 0, (size_t)NA * 128 * sizeof(float), stream);
    k1_p12 <<<782,   256, 0, stream>>>(atom, W, P12);
    k2s    <<<NBLK2, 256, 0, stream>>>(nbr, nidx, W, P12, partial1);
    k2b_bn1<<<256,    64, 0, stream>>>(partial1, gamma1, beta1, bn1);
    k3r    <<<NBLK2, 256, 0, stream>>>(nbr, nidx, W, P12, bn1, nsum);
    k3s    <<<NBLK3, 256, 0, stream>>>(nsum, partial2);
    k3b_bn2<<<128,    64, 0, stream>>>(partial2, gamma2, beta2, bn2);
    k4_out <<<6250,  256, 0, stream>>>(atom, nsum, bn2, out);
}